// Round 3
// baseline (46.622 us; speedup 1.0000x reference)
//
#include <hip/hip_runtime.h>
#include <stdint.h>

// Problem constants (from reference):
#define T_DIM 1024
#define B_DIM 8
#define C_DIM 1024
#define H_DIM 16
#define K_SZ  7
#define P_PAD 3
#define O_DIM (H_DIM * K_SZ)   // 112
#define TB    (T_DIM * B_DIM)  // 8192 rows

typedef __attribute__((ext_vector_type(8))) short bf16x8;  // 4 VGPRs, 8 bf16
typedef __attribute__((ext_vector_type(4))) float f32x4;
typedef __attribute__((ext_vector_type(2))) uint32_t u32x2;

union FragU { uint32_t u[4]; bf16x8 v; };

// RNE fp32->bf16 pack of two floats into one dword (lo=a, hi=b)
__device__ inline uint32_t pk_bf16(float a, float b) {
  uint32_t ua = __float_as_uint(a), ub = __float_as_uint(b);
  ua += 0x7FFFu + ((ua >> 16) & 1u);
  ub += 0x7FFFu + ((ub >> 16) & 1u);
  return (ua >> 16) | (ub & 0xFFFF0000u);
}

__device__ inline bf16x8 load_bf16x8_cvt(const float* __restrict__ p) {
  float4 lo = *reinterpret_cast<const float4*>(p);
  float4 hi = *reinterpret_cast<const float4*>(p + 4);
  FragU f;
  f.u[0] = pk_bf16(lo.x, lo.y);
  f.u[1] = pk_bf16(lo.z, lo.w);
  f.u[2] = pk_bf16(hi.x, hi.y);
  f.u[3] = pk_bf16(hi.z, hi.w);
  return f.v;
}

// Kernel 0: one-time W_lin fp32 -> bf16 (row-major, same layout).
// 112*1024 = 114688 elements; 8 per thread -> 56 blocks x 256.
__global__ __launch_bounds__(256) void prep_w_kernel(
    const float* __restrict__ Wl, uint32_t* __restrict__ Wbf /*as dwords*/) {
  const int i = (blockIdx.x * 256 + threadIdx.x) * 8;
  FragU f;
  f.v = load_bf16x8_cvt(Wl + i);
  *reinterpret_cast<bf16x8*>(Wbf + i / 2) = f.v;
}

// Kernel 1: w = softmax_over_K( x @ W_lin^T + b_lin ) via bf16 MFMA.
// Block: 256 threads = 4 waves; tile = 16 rows x 112 cols.
// Waves K-split (256 each). A staged coalesced->LDS (XOR-swizzled bf16);
// B per-lane 16B loads from L2-resident bf16 W. LDS region per wave is
// reused for the fp32 partials (no cross-wave hazard: each wave finishes
// reading its own x-slice before overwriting it with its own partials).
template <bool PREPPED>
__global__ __launch_bounds__(256) void logits_mfma_kernel(
    const float* __restrict__ x, const float* __restrict__ Wl,
    const uint16_t* __restrict__ Wbf, const float* __restrict__ bl,
    float* __restrict__ wout) {
  __shared__ char buf[4 * 8192];   // per-wave 8KB: x_bf16[16][256] OR part f32[16][116]

  const int tid  = threadIdx.x;
  const int wv   = tid >> 6;
  const int lane = tid & 63;
  const int l15  = lane & 15;
  const int oct  = lane >> 4;
  const int rb   = blockIdx.x * 16;   // 512 blocks
  const int kw   = wv * 256;          // this wave's K range
  char* wbuf_lds = buf + wv * 8192;

  // --- stage x[rb..rb+15][kw..kw+255] -> bf16 LDS, swizzled ---
  {
    const float* __restrict__ xs = x + (size_t)rb * C_DIM + kw;
#pragma unroll
    for (int r = 0; r < 16; ++r) {
      float4 v = *reinterpret_cast<const float4*>(xs + (size_t)r * C_DIM + lane * 4);
      u32x2 d;
      d.x = pk_bf16(v.x, v.y);
      d.y = pk_bf16(v.z, v.w);
      int byte = r * 512 + ((lane * 8) ^ ((r & 7) << 4));
      *reinterpret_cast<u32x2*>(wbuf_lds + byte) = d;
    }
  }
  // only intra-wave LDS dependence (each wave reads its own region), but
  // ds_write->ds_read needs the waitcnt; syncthreads is the simple fence.
  __syncthreads();

  f32x4 acc[7];
#pragma unroll
  for (int nf = 0; nf < 7; ++nf) acc[nf] = (f32x4)(0.f);

#pragma unroll
  for (int ks = 0; ks < 8; ++ks) {
    int abyte = l15 * 512 + (((oct * 16) + ks * 64) ^ ((l15 & 7) << 4));
    bf16x8 a = *reinterpret_cast<const bf16x8*>(wbuf_lds + abyte);
#pragma unroll
    for (int nf = 0; nf < 7; ++nf) {
      bf16x8 b;
      if (PREPPED) {
        b = *reinterpret_cast<const bf16x8*>(
            Wbf + (size_t)(nf * 16 + l15) * C_DIM + kw + ks * 32 + oct * 8);
      } else {
        b = load_bf16x8_cvt(Wl + (size_t)(nf * 16 + l15) * C_DIM + kw + ks * 32 + oct * 8);
      }
      acc[nf] = __builtin_amdgcn_mfma_f32_16x16x32_bf16(a, b, acc[nf], 0, 0, 0);
    }
  }

  // D layout: col = lane&15, row = (lane>>4)*4 + reg
  // partials: per-wave fp32 [16][116] overlaid on this wave's x region
  float* part = reinterpret_cast<float*>(wbuf_lds);
#pragma unroll
  for (int nf = 0; nf < 7; ++nf)
#pragma unroll
    for (int r = 0; r < 4; ++r)
      part[(oct * 4 + r) * 116 + nf * 16 + l15] = acc[nf][r];

  __syncthreads();

  // Reduce 4 K-partials + bias + softmax over 7 taps. 256 (row,head) pairs.
  {
    const int row = tid >> 4;
    const int h   = tid & 15;
    float lg[7];
    float m = -1e30f;
#pragma unroll
    for (int j = 0; j < 7; ++j) {
      const int c = h * 7 + j;
      const int o = row * 116 + c;
      float sum = reinterpret_cast<float*>(buf)[o]
                + reinterpret_cast<float*>(buf + 8192)[o]
                + reinterpret_cast<float*>(buf + 16384)[o]
                + reinterpret_cast<float*>(buf + 24576)[o] + bl[c];
      lg[j] = sum;
      m = fmaxf(m, sum);
    }
    float s = 0.f;
#pragma unroll
    for (int j = 0; j < 7; ++j) { lg[j] = __expf(lg[j] - m); s += lg[j]; }
    const float inv = 1.0f / s;
    float* __restrict__ op = wout + (size_t)(rb + row) * O_DIM + h * 7;
#pragma unroll
    for (int j = 0; j < 7; ++j) op[j] = lg[j] * inv;
  }
}

// Kernel 2: out[t,b,c] = sum_j w[t,b,h(c),j] * x[t-3+j, b, c] + bias[c]
__global__ __launch_bounds__(256) void dynconv_kernel(
    const float* __restrict__ x, const float* __restrict__ w,
    const float* __restrict__ bias, float* __restrict__ out) {
  const int row = blockIdx.x;   // t*B + b
  const int t   = row >> 3;
  const int b   = row & 7;
  const int tid = threadIdx.x;
  const int c4  = tid << 2;
  const int h   = c4 >> 6;      // R = 64 channels per head
  const float* __restrict__ wr = w + (size_t)row * O_DIM + h * K_SZ;

  float ax = 0.f, ay = 0.f, az = 0.f, aw = 0.f;
#pragma unroll
  for (int j = 0; j < K_SZ; ++j) {
    int st = t - P_PAD + j;
    if (st < 0 || st >= T_DIM) continue;
    float wj = wr[j];
    const float4 xv = *reinterpret_cast<const float4*>(
        x + ((size_t)(st * B_DIM + b)) * C_DIM + c4);
    ax += wj * xv.x;
    ay += wj * xv.y;
    az += wj * xv.z;
    aw += wj * xv.w;
  }
  float4 bv = *reinterpret_cast<const float4*>(bias + c4);
  float4 o4 = make_float4(ax + bv.x, ay + bv.y, az + bv.z, aw + bv.w);
  *reinterpret_cast<float4*>(out + (size_t)row * C_DIM + c4) = o4;
}

extern "C" void kernel_launch(void* const* d_in, const int* in_sizes, int n_in,
                              void* d_out, int out_size, void* d_ws, size_t ws_size,
                              hipStream_t stream) {
  const float* x  = (const float*)d_in[0];   // (T,B,C)
  const float* Wl = (const float*)d_in[1];   // (H*K, C)
  const float* bl = (const float*)d_in[2];   // (H*K,)
  const float* cb = (const float*)d_in[3];   // (C,)
  float* out = (float*)d_out;                // (T,B,C)

  const size_t WBF_BYTES = (size_t)O_DIM * C_DIM * 2;       // 229376
  const size_t WBUF_BYTES = (size_t)TB * O_DIM * 4;         // 3.67 MB
  const bool prepped = ws_size >= 262144 + WBUF_BYTES;

  if (prepped) {
    uint32_t* wbf = (uint32_t*)d_ws;                        // bf16 W, 224KB
    float* wbuf   = (float*)((char*)d_ws + 262144);         // softmax weights
    prep_w_kernel<<<O_DIM * C_DIM / (256 * 8), 256, 0, stream>>>(Wl, wbf);
    logits_mfma_kernel<true><<<TB / 16, 256, 0, stream>>>(
        x, Wl, (const uint16_t*)wbf, bl, wbuf);
    dynconv_kernel<<<TB, 256, 0, stream>>>(x, wbuf, cb, out);
  } else {
    float* wbuf = (float*)d_ws;
    logits_mfma_kernel<false><<<TB / 16, 256, 0, stream>>>(
        x, Wl, nullptr, bl, wbuf);
    dynconv_kernel<<<TB, 256, 0, stream>>>(x, wbuf, cb, out);
  }
}

// Round 4
// 40.034 us; speedup vs baseline: 1.1646x; 1.1646x over previous
//
#include <hip/hip_runtime.h>
#include <stdint.h>

// Problem constants (from reference):
#define T_DIM 1024
#define B_DIM 8
#define C_DIM 1024
#define H_DIM 16
#define K_SZ  7
#define P_PAD 3
#define O_DIM (H_DIM * K_SZ)   // 112
#define TB    (T_DIM * B_DIM)  // 8192 rows

typedef __attribute__((ext_vector_type(8))) short bf16x8;  // 4 VGPRs, 8 bf16
typedef __attribute__((ext_vector_type(4))) float f32x4;
typedef __attribute__((ext_vector_type(2))) uint32_t u32x2;

union FragU { uint32_t u[4]; bf16x8 v; };

// RNE fp32->bf16 pack of two floats into one dword (lo=a, hi=b)
__device__ inline uint32_t pk_bf16(float a, float b) {
  uint32_t ua = __float_as_uint(a), ub = __float_as_uint(b);
  ua += 0x7FFFu + ((ua >> 16) & 1u);
  ub += 0x7FFFu + ((ub >> 16) & 1u);
  return (ua >> 16) | (ub & 0xFFFF0000u);
}

__device__ inline bf16x8 load_bf16x8_cvt(const float* __restrict__ p) {
  float4 lo = *reinterpret_cast<const float4*>(p);
  float4 hi = *reinterpret_cast<const float4*>(p + 4);
  FragU f;
  f.u[0] = pk_bf16(lo.x, lo.y);
  f.u[1] = pk_bf16(lo.z, lo.w);
  f.u[2] = pk_bf16(hi.x, hi.y);
  f.u[3] = pk_bf16(hi.z, hi.w);
  return f.v;
}

// Kernel 0: build fragment-native bf16 W.
// Wf[((ks*7)+nf)*64 + lane] (16B each) = W[nf*16+(lane&15)][ks*32+(lane>>4)*8 .. +7]
// so the hot kernel's B-load is base + tid*16B: perfectly coalesced.
// 32 ks-steps x 7 nf x 64 lanes = 14336 fragments -> 56 blocks x 256.
__global__ __launch_bounds__(256) void prep_wfrag_kernel(
    const float* __restrict__ Wl, uint16_t* __restrict__ Wf) {
  const int t  = blockIdx.x * 256 + threadIdx.x;  // 0..14335
  const int f  = t >> 6;
  const int l  = t & 63;
  const int ks = f / 7;
  const int nf = f - ks * 7;
  const int row = nf * 16 + (l & 15);
  const int kb  = ks * 32 + (l >> 4) * 8;
  bf16x8 v = load_bf16x8_cvt(Wl + (size_t)row * C_DIM + kb);
  *reinterpret_cast<bf16x8*>(Wf + (size_t)t * 8) = v;   // coalesced 16B/lane
}

// Kernel 1: w = softmax_over_K( x @ W_lin^T + b_lin ) via bf16 MFMA.
// Block: 256 threads = 4 waves; tile = 16 rows. Waves K-split (256 each).
// A: coalesced fp32 loads -> bf16 -> XOR-swizzled LDS -> ds_read_b128.
// B: fragment-native Wf, coalesced 1KB/instruction, L2-resident.
// Per-wave LDS region reused for fp32 partials after MFMA.
template <bool PREPPED>
__global__ __launch_bounds__(256) void logits_mfma_kernel(
    const float* __restrict__ x, const float* __restrict__ Wl,
    const uint16_t* __restrict__ Wf, const float* __restrict__ bl,
    float* __restrict__ wout) {
  __shared__ char buf[4 * 8192];  // per-wave 8KB: x_bf16[16][256] OR part f32[16][116]

  const int tid  = threadIdx.x;
  const int wv   = tid >> 6;
  const int lane = tid & 63;
  const int l15  = lane & 15;
  const int oct  = lane >> 4;
  const int rb   = blockIdx.x * 16;   // 512 blocks
  const int kw   = wv * 256;          // this wave's K range
  char* lds = buf + wv * 8192;

  // --- stage x[rb..rb+15][kw..kw+255] -> bf16 LDS, XOR-swizzled ---
  {
    const float* __restrict__ xs = x + (size_t)rb * C_DIM + kw;
#pragma unroll
    for (int r = 0; r < 16; ++r) {
      float4 v = *reinterpret_cast<const float4*>(xs + (size_t)r * C_DIM + lane * 4);
      u32x2 d;
      d.x = pk_bf16(v.x, v.y);
      d.y = pk_bf16(v.z, v.w);
      int byte = r * 512 + ((lane * 8) ^ ((r & 7) << 4));
      *reinterpret_cast<u32x2*>(lds + byte) = d;
    }
  }
  __syncthreads();

  f32x4 acc[7];
#pragma unroll
  for (int nf = 0; nf < 7; ++nf) acc[nf] = (f32x4)(0.f);

#pragma unroll
  for (int ks = 0; ks < 8; ++ks) {
    const int abyte = l15 * 512 + (((oct * 16) + ks * 64) ^ ((l15 & 7) << 4));
    bf16x8 a = *reinterpret_cast<const bf16x8*>(lds + abyte);
#pragma unroll
    for (int nf = 0; nf < 7; ++nf) {
      bf16x8 b;
      if (PREPPED) {
        // fragment-native: 64 lanes read 1KB contiguous
        b = *reinterpret_cast<const bf16x8*>(
            Wf + ((size_t)(((wv * 8 + ks) * 7 + nf) * 64) + lane) * 8);
      } else {
        b = load_bf16x8_cvt(Wl + (size_t)(nf * 16 + l15) * C_DIM + kw + ks * 32 + oct * 8);
      }
      acc[nf] = __builtin_amdgcn_mfma_f32_16x16x32_bf16(a, b, acc[nf], 0, 0, 0);
    }
  }

  // D layout: col = lane&15 (W row), row = (lane>>4)*4 + reg (x row).
  // partials: per-wave fp32 [16][116] overlaid on this wave's x region.
  float* part = reinterpret_cast<float*>(lds);
#pragma unroll
  for (int nf = 0; nf < 7; ++nf)
#pragma unroll
    for (int r = 0; r < 4; ++r)
      part[(oct * 4 + r) * 116 + nf * 16 + l15] = acc[nf][r];

  __syncthreads();

  // Reduce 4 K-partials + bias + softmax over 7 taps. 256 (row,head) pairs.
  {
    const int row = tid >> 4;
    const int h   = tid & 15;
    float lg[7];
    float m = -1e30f;
#pragma unroll
    for (int j = 0; j < 7; ++j) {
      const int c = h * 7 + j;
      const int o = row * 116 + c;
      float sum = reinterpret_cast<float*>(buf)[o]
                + reinterpret_cast<float*>(buf + 8192)[o]
                + reinterpret_cast<float*>(buf + 16384)[o]
                + reinterpret_cast<float*>(buf + 24576)[o] + bl[c];
      lg[j] = sum;
      m = fmaxf(m, sum);
    }
    float s = 0.f;
#pragma unroll
    for (int j = 0; j < 7; ++j) { lg[j] = __expf(lg[j] - m); s += lg[j]; }
    const float inv = 1.0f / s;
    float* __restrict__ op = wout + (size_t)(rb + row) * O_DIM + h * 7;
#pragma unroll
    for (int j = 0; j < 7; ++j) op[j] = lg[j] * inv;
  }
}

// Kernel 2: out[t,b,c] = sum_j w[t,b,h(c),j] * x[t-3+j, b, c] + bias[c]
// At its HBM floor (~68MB traffic): x read ~once (L3 absorbs the 7x), out written once.
__global__ __launch_bounds__(256) void dynconv_kernel(
    const float* __restrict__ x, const float* __restrict__ w,
    const float* __restrict__ bias, float* __restrict__ out) {
  const int row = blockIdx.x;   // t*B + b
  const int t   = row >> 3;
  const int b   = row & 7;
  const int tid = threadIdx.x;
  const int c4  = tid << 2;
  const int h   = c4 >> 6;      // R = 64 channels per head
  const float* __restrict__ wr = w + (size_t)row * O_DIM + h * K_SZ;

  float ax = 0.f, ay = 0.f, az = 0.f, aw = 0.f;
#pragma unroll
  for (int j = 0; j < K_SZ; ++j) {
    int st = t - P_PAD + j;
    if (st < 0 || st >= T_DIM) continue;
    float wj = wr[j];
    const float4 xv = *reinterpret_cast<const float4*>(
        x + ((size_t)(st * B_DIM + b)) * C_DIM + c4);
    ax += wj * xv.x;
    ay += wj * xv.y;
    az += wj * xv.z;
    aw += wj * xv.w;
  }
  float4 bv = *reinterpret_cast<const float4*>(bias + c4);
  float4 o4 = make_float4(ax + bv.x, ay + bv.y, az + bv.z, aw + bv.w);
  *reinterpret_cast<float4*>(out + (size_t)row * C_DIM + c4) = o4;
}

extern "C" void kernel_launch(void* const* d_in, const int* in_sizes, int n_in,
                              void* d_out, int out_size, void* d_ws, size_t ws_size,
                              hipStream_t stream) {
  const float* x  = (const float*)d_in[0];   // (T,B,C)
  const float* Wl = (const float*)d_in[1];   // (H*K, C)
  const float* bl = (const float*)d_in[2];   // (H*K,)
  const float* cb = (const float*)d_in[3];   // (C,)
  float* out = (float*)d_out;                // (T,B,C)

  const size_t WF_BYTES   = 262144;                    // 224KB frag-W, padded
  const size_t WBUF_BYTES = (size_t)TB * O_DIM * 4;    // 3.67 MB
  const bool prepped = ws_size >= WF_BYTES + WBUF_BYTES;

  if (prepped) {
    uint16_t* wf = (uint16_t*)d_ws;
    float* wbuf  = (float*)((char*)d_ws + WF_BYTES);
    prep_wfrag_kernel<<<(32 * 7 * 64) / 256, 256, 0, stream>>>(Wl, wf);
    logits_mfma_kernel<true><<<TB / 16, 256, 0, stream>>>(x, Wl, wf, bl, wbuf);
    dynconv_kernel<<<TB, 256, 0, stream>>>(x, wbuf, cb, out);
  } else {
    float* wbuf = (float*)d_ws;
    logits_mfma_kernel<false><<<TB / 16, 256, 0, stream>>>(x, Wl, nullptr, bl, wbuf);
    dynconv_kernel<<<TB, 256, 0, stream>>>(x, wbuf, cb, out);
  }
}

// Round 5
// 30.263 us; speedup vs baseline: 1.5406x; 1.3229x over previous
//
#include <hip/hip_runtime.h>
#include <stdint.h>

// Problem constants (from reference):
#define T_DIM 1024
#define B_DIM 8
#define C_DIM 1024
#define H_DIM 16
#define K_SZ  7
#define P_PAD 3
#define O_DIM (H_DIM * K_SZ)   // 112
#define TB    (T_DIM * B_DIM)  // 8192 rows

typedef __attribute__((ext_vector_type(8))) short bf16x8;  // 4 VGPRs, 8 bf16
typedef __attribute__((ext_vector_type(4))) float f32x4;
typedef __attribute__((ext_vector_type(2))) uint32_t u32x2;

union FragU { uint32_t u[4]; bf16x8 v; };

// RNE fp32->bf16 pack of two floats into one dword (lo=a, hi=b)
__device__ inline uint32_t pk_bf16(float a, float b) {
  uint32_t ua = __float_as_uint(a), ub = __float_as_uint(b);
  ua += 0x7FFFu + ((ua >> 16) & 1u);
  ub += 0x7FFFu + ((ub >> 16) & 1u);
  return (ua >> 16) | (ub & 0xFFFF0000u);
}

__device__ inline bf16x8 load_bf16x8_cvt(const float* __restrict__ p) {
  float4 lo = *reinterpret_cast<const float4*>(p);
  float4 hi = *reinterpret_cast<const float4*>(p + 4);
  FragU f;
  f.u[0] = pk_bf16(lo.x, lo.y);
  f.u[1] = pk_bf16(lo.z, lo.w);
  f.u[2] = pk_bf16(hi.x, hi.y);
  f.u[3] = pk_bf16(hi.z, hi.w);
  return f.v;
}

// Kernel 0: build fragment-native bf16 W.
// Wf[((ks*7)+nf)*64 + lane] (16B) = W[nf*16+(lane&15)][ks*32+(lane>>4)*8 .. +7]
__global__ __launch_bounds__(256) void prep_wfrag_kernel(
    const float* __restrict__ Wl, uint16_t* __restrict__ Wf) {
  const int t  = blockIdx.x * 256 + threadIdx.x;  // 0..14335
  const int f  = t >> 6;
  const int l  = t & 63;
  const int ks = f / 7;
  const int nf = f - ks * 7;
  const int row = nf * 16 + (l & 15);
  const int kb  = ks * 32 + (l >> 4) * 8;
  bf16x8 v = load_bf16x8_cvt(Wl + (size_t)row * C_DIM + kb);
  *reinterpret_cast<bf16x8*>(Wf + (size_t)t * 8) = v;   // coalesced 16B/lane
}

// Fused kernel: per block of 16 (t,b) rows:
//   phase 1: stage x rows -> bf16 LDS (XOR-swizzled)
//   phase 2: logits via MFMA (waves K-split, B = fragment-native coalesced)
//   phase 3: LDS partial reduce + bias + softmax -> w_s[16][112] in LDS
//   phase 4: dynamic conv for the same 16 rows (taps from L1/L2-hot x), +bias
// No global weight buffer, no second kernel, no scattered global stores.
template <bool PREPPED>
__global__ __launch_bounds__(256) void fused_dynconv_kernel(
    const float* __restrict__ x, const float* __restrict__ Wl,
    const uint16_t* __restrict__ Wf, const float* __restrict__ bl,
    const float* __restrict__ cb, float* __restrict__ out) {
  __shared__ char buf[4 * 8192];    // per-wave 8KB: x_bf16[16][256] OR part f32[16][116]
  __shared__ float w_s[16][113];    // softmax weights [row][h*7+j], pad 113

  const int tid  = threadIdx.x;
  const int wv   = tid >> 6;
  const int lane = tid & 63;
  const int l15  = lane & 15;
  const int oct  = lane >> 4;
  // XCD-chunk swizzle: 512 blocks = 8 XCDs x 64 contiguous chunks (bijective)
  const int bid  = blockIdx.x;
  const int swz  = (bid & 7) * 64 + (bid >> 3);
  const int rb   = swz * 16;
  const int kw   = wv * 256;          // this wave's K range
  char* lds = buf + wv * 8192;

  // --- phase 1: stage x[rb..rb+15][kw..kw+255] -> bf16 LDS, XOR-swizzled ---
  {
    const float* __restrict__ xs = x + (size_t)rb * C_DIM + kw;
#pragma unroll
    for (int r = 0; r < 16; ++r) {
      float4 v = *reinterpret_cast<const float4*>(xs + (size_t)r * C_DIM + lane * 4);
      u32x2 d;
      d.x = pk_bf16(v.x, v.y);
      d.y = pk_bf16(v.z, v.w);
      int byte = r * 512 + ((lane * 8) ^ ((r & 7) << 4));
      *reinterpret_cast<u32x2*>(lds + byte) = d;
    }
  }
  __syncthreads();

  // --- phase 2: MFMA ---
  f32x4 acc[7];
#pragma unroll
  for (int nf = 0; nf < 7; ++nf) acc[nf] = (f32x4)(0.f);

#pragma unroll
  for (int ks = 0; ks < 8; ++ks) {
    const int abyte = l15 * 512 + (((oct * 16) + ks * 64) ^ ((l15 & 7) << 4));
    bf16x8 a = *reinterpret_cast<const bf16x8*>(lds + abyte);
#pragma unroll
    for (int nf = 0; nf < 7; ++nf) {
      bf16x8 b;
      if (PREPPED) {
        b = *reinterpret_cast<const bf16x8*>(
            Wf + ((size_t)(((wv * 8 + ks) * 7 + nf) * 64) + lane) * 8);
      } else {
        b = load_bf16x8_cvt(Wl + (size_t)(nf * 16 + l15) * C_DIM + kw + ks * 32 + oct * 8);
      }
      acc[nf] = __builtin_amdgcn_mfma_f32_16x16x32_bf16(a, b, acc[nf], 0, 0, 0);
    }
  }

  // D layout: col = lane&15 (W row), row = (lane>>4)*4 + reg (x row).
  // partials: per-wave fp32 [16][116] overlaid on this wave's x region.
  {
    float* part = reinterpret_cast<float*>(lds);
#pragma unroll
    for (int nf = 0; nf < 7; ++nf)
#pragma unroll
      for (int r = 0; r < 4; ++r)
        part[(oct * 4 + r) * 116 + nf * 16 + l15] = acc[nf][r];
  }
  __syncthreads();

  // --- phase 3: reduce partials + bias + softmax -> w_s (LDS only) ---
  {
    const int row = tid >> 4;
    const int h   = tid & 15;
    float lg[7];
    float m = -1e30f;
#pragma unroll
    for (int j = 0; j < 7; ++j) {
      const int c = h * 7 + j;
      const int o = row * 116 + c;
      float sum = reinterpret_cast<float*>(buf)[o]
                + reinterpret_cast<float*>(buf + 8192)[o]
                + reinterpret_cast<float*>(buf + 16384)[o]
                + reinterpret_cast<float*>(buf + 24576)[o] + bl[c];
      lg[j] = sum;
      m = fmaxf(m, sum);
    }
    float s = 0.f;
#pragma unroll
    for (int j = 0; j < 7; ++j) { lg[j] = __expf(lg[j] - m); s += lg[j]; }
    const float inv = 1.0f / s;
#pragma unroll
    for (int j = 0; j < 7; ++j) w_s[row][h * 7 + j] = lg[j] * inv;
  }
  __syncthreads();

  // --- phase 4: dynamic conv for the same 16 rows ---
  // thread (row, t15): channels {i*64 + t15*4 .. +3} for i = head = 0..15.
  // Per i: w broadcast from w_s[row][i*7+j]; taps L1-resident (7 rows x 4KB).
  {
    const int row = tid >> 4;
    const int t15 = tid & 15;
    const int rg  = rb + row;
    const int tt  = rg >> 3;
    const int bb  = rg & 7;
    const float* __restrict__ wrow = &w_s[row][0];

    size_t xoff[7];
    bool ok[7];
#pragma unroll
    for (int j = 0; j < 7; ++j) {
      int tp = tt + j - P_PAD;
      ok[j] = (tp >= 0) && (tp < T_DIM);
      int tpc = min(max(tp, 0), T_DIM - 1);
      xoff[j] = (size_t)(tpc * B_DIM + bb) * C_DIM;
    }

#pragma unroll 4
    for (int i = 0; i < 16; ++i) {
      const int ch = i * 64 + t15 * 4;
      float4 a4 = *reinterpret_cast<const float4*>(cb + ch);
#pragma unroll
      for (int j = 0; j < 7; ++j) {
        float wj = ok[j] ? wrow[i * 7 + j] : 0.f;
        float4 xv = *reinterpret_cast<const float4*>(x + xoff[j] + ch);
        a4.x += wj * xv.x;
        a4.y += wj * xv.y;
        a4.z += wj * xv.z;
        a4.w += wj * xv.w;
      }
      *reinterpret_cast<float4*>(out + (size_t)rg * C_DIM + ch) = a4;
    }
  }
}

extern "C" void kernel_launch(void* const* d_in, const int* in_sizes, int n_in,
                              void* d_out, int out_size, void* d_ws, size_t ws_size,
                              hipStream_t stream) {
  const float* x  = (const float*)d_in[0];   // (T,B,C)
  const float* Wl = (const float*)d_in[1];   // (H*K, C)
  const float* bl = (const float*)d_in[2];   // (H*K,)
  const float* cb = (const float*)d_in[3];   // (C,)
  float* out = (float*)d_out;                // (T,B,C)

  const size_t WF_BYTES = 262144;            // 224KB frag-W, padded
  const bool prepped = ws_size >= WF_BYTES;

  if (prepped) {
    uint16_t* wf = (uint16_t*)d_ws;
    prep_wfrag_kernel<<<(32 * 7 * 64) / 256, 256, 0, stream>>>(Wl, wf);
    fused_dynconv_kernel<true><<<TB / 16, 256, 0, stream>>>(x, Wl, wf, bl, cb, out);
  } else {
    fused_dynconv_kernel<false><<<TB / 16, 256, 0, stream>>>(x, Wl, nullptr, bl, cb, out);
  }
}